// Round 5
// baseline (409.050 us; speedup 1.0000x reference)
//
#include <hip/hip_runtime.h>
#include <math.h>

// ---------------------------------------------------------------------------
// 2-layer graph conv (1-wide features), atomic-free via dst-binned counting
// sort (once, reused by both layers) + per-bin LDS accumulation.
//   layer: agg[v] = sum_{(u->v)} x[u];  x = relu(agg * w[i])
//   out   = sigmoid(x + bias)
// Packing: N <= 2^20, BINSZ=2048 -> entry = (dst_low11 << 20) | src20
// R5: scatter_staged2 (1024 thr, 1 LDS-atomic pass w/ reg-cached ranks,
//     shfl scan, nt streams) + reduce_split nt binned loads (protect x in L2)
//     + 8-deep gather MLP.
// ---------------------------------------------------------------------------

#define BINSHIFT 11
#define BINSZ    2048
#define MAXNB    512
#define SCHUNK   16384
#define STH2     1024
#define SPLIT    4
#define SPLITSH  2

typedef int      i32x4 __attribute__((ext_vector_type(4)));
typedef unsigned u32x4 __attribute__((ext_vector_type(4)));
typedef float    f32x4 __attribute__((ext_vector_type(4)));

// A1: per-bin edge counts
__global__ void count_bins(const int* __restrict__ dst, int nE, int NB,
                           int* __restrict__ counts) {
    __shared__ int h[MAXNB];
    for (int t = threadIdx.x; t < MAXNB; t += blockDim.x) h[t] = 0;
    __syncthreads();
    int tid = blockIdx.x * blockDim.x + threadIdx.x;
    int stride = gridDim.x * blockDim.x;
    int nE4 = nE >> 2;
    const i32x4* d4 = reinterpret_cast<const i32x4*>(dst);
    for (int i = tid; i < nE4; i += stride) {
        i32x4 d = __builtin_nontemporal_load(&d4[i]);
        atomicAdd(&h[d.x >> BINSHIFT], 1);
        atomicAdd(&h[d.y >> BINSHIFT], 1);
        atomicAdd(&h[d.z >> BINSHIFT], 1);
        atomicAdd(&h[d.w >> BINSHIFT], 1);
    }
    for (int e = (nE4 << 2) + tid; e < nE; e += stride)
        atomicAdd(&h[dst[e] >> BINSHIFT], 1);
    __syncthreads();
    for (int t = threadIdx.x; t < NB; t += blockDim.x)
        if (h[t]) atomicAdd(&counts[t], h[t]);
}

// A2: exclusive scan of NB (<=512) counts -> offsets[NB+1], cursors
__global__ void scan_bins(const int* __restrict__ counts, int* __restrict__ offsets,
                          int* __restrict__ cursors, int NB) {
    __shared__ int s[MAXNB];
    int t = threadIdx.x;
    int c = (t < NB) ? counts[t] : 0;
    s[t] = c;
    __syncthreads();
    for (int off = 1; off < MAXNB; off <<= 1) {
        int v = (t >= off) ? s[t - off] : 0;
        __syncthreads();
        s[t] += v;
        __syncthreads();
    }
    if (t < NB) {
        int excl = s[t] - c;
        offsets[t] = excl;
        cursors[t] = excl;
        if (t == NB - 1) offsets[NB] = s[t];
    }
}

// A3 (R5): 1024-thread staged scatter, full chunks ONLY (16 edges/thread).
// Single LDS-atomic pass: rank cached in registers (fully unrolled => VGPRs).
__global__ __launch_bounds__(STH2, 8)   // 8 waves/EU => 2 blocks/CU
void scatter_staged2(const int* __restrict__ src, const int* __restrict__ dst,
                     int NB, int* __restrict__ cursors,
                     unsigned int* __restrict__ binned) {
    __shared__ unsigned int stage[SCHUNK];   // 64 KB
    __shared__ int cnt[MAXNB];
    __shared__ int lstart[MAXNB];
    __shared__ int delta[MAXNB];
    __shared__ int wsum[8];

    int t = threadIdx.x;
    int cb = blockIdx.x * SCHUNK;
    int wid = t >> 6, lane = t & 63;

    if (t < MAXNB) cnt[t] = 0;
    __syncthreads();

    // ---- pass 1: count + rank (single LDS-atomic pass), ranks in regs ----
    unsigned rp[16];
    const i32x4* d4 = reinterpret_cast<const i32x4*>(dst + cb);
    #pragma unroll
    for (int k = 0; k < 4; ++k) {
        i32x4 d = __builtin_nontemporal_load(&d4[k * STH2 + t]);
        int b0 = d.x >> BINSHIFT, b1 = d.y >> BINSHIFT;
        int b2 = d.z >> BINSHIFT, b3 = d.w >> BINSHIFT;
        int r0 = atomicAdd(&cnt[b0], 1);
        int r1 = atomicAdd(&cnt[b1], 1);
        int r2 = atomicAdd(&cnt[b2], 1);
        int r3 = atomicAdd(&cnt[b3], 1);
        rp[k * 4 + 0] = ((unsigned)b0 << 14) | (unsigned)r0;
        rp[k * 4 + 1] = ((unsigned)b1 << 14) | (unsigned)r1;
        rp[k * 4 + 2] = ((unsigned)b2 << 14) | (unsigned)r2;
        rp[k * 4 + 3] = ((unsigned)b3 << 14) | (unsigned)r3;
    }
    __syncthreads();

    // ---- exclusive scan of cnt[0..511] via shfl (waves 0-7) ----
    int myc = 0, pre = 0;
    if (t < MAXNB) {
        myc = cnt[t];
        int v = myc;
        #pragma unroll
        for (int d = 1; d < 64; d <<= 1) {
            int u = __shfl_up(v, d, 64);
            if (lane >= d) v += u;
        }
        if (lane == 63) wsum[wid] = v;
        pre = v - myc;
    }
    __syncthreads();
    if (t < MAXNB) {
        int base = 0;
        #pragma unroll
        for (int k = 0; k < 8; ++k) base += (k < wid) ? wsum[k] : 0;
        lstart[t] = base + pre;
        // reserve global space (one atomic per non-empty bin)
        int gb = 0;
        if (t < NB && myc) gb = atomicAdd(&cursors[t], myc);
        delta[t] = gb - (base + pre);
    }
    __syncthreads();

    // ---- pass 2: reload dst (L2-hot) + src, write stage bin-ordered ----
    const i32x4* s4 = reinterpret_cast<const i32x4*>(src + cb);
    #pragma unroll
    for (int k = 0; k < 4; ++k) {
        i32x4 d = d4[k * STH2 + t];
        i32x4 s = __builtin_nontemporal_load(&s4[k * STH2 + t]);
        unsigned q;
        q = rp[k * 4 + 0];
        stage[lstart[q >> 14] + (q & 0x3FFFu)] = ((unsigned)(d.x & (BINSZ - 1)) << 20) | (unsigned)s.x;
        q = rp[k * 4 + 1];
        stage[lstart[q >> 14] + (q & 0x3FFFu)] = ((unsigned)(d.y & (BINSZ - 1)) << 20) | (unsigned)s.y;
        q = rp[k * 4 + 2];
        stage[lstart[q >> 14] + (q & 0x3FFFu)] = ((unsigned)(d.z & (BINSZ - 1)) << 20) | (unsigned)s.z;
        q = rp[k * 4 + 3];
        stage[lstart[q >> 14] + (q & 0x3FFFu)] = ((unsigned)(d.w & (BINSZ - 1)) << 20) | (unsigned)s.w;
    }
    __syncthreads();

    // ---- copy-out: one wave per bin, coalesced segment copy ----
    for (int b = wid; b < NB; b += STH2 / 64) {
        int s0 = lstart[b];
        int s1 = s0 + cnt[b];
        int dlt = delta[b];
        for (int j = s0 + lane; j < s1; j += 64)
            __builtin_nontemporal_store(stage[j], &binned[dlt + j]);
    }
}

// A3b: tail scatter (< SCHUNK edges), single block, slow 2-pass version.
__global__ void scatter_tail(const int* __restrict__ src, const int* __restrict__ dst,
                             int start, int nE, int NB, int* __restrict__ cursors,
                             unsigned int* __restrict__ binned) {
    __shared__ unsigned int stage[SCHUNK];
    __shared__ int cnt[MAXNB], lstart[MAXNB], lscan[MAXNB], delta[MAXNB];
    int t = threadIdx.x;          // 512
    int nHere = nE - start;
    cnt[t] = 0;
    __syncthreads();
    for (int j = t; j < nHere; j += 512)
        atomicAdd(&cnt[dst[start + j] >> BINSHIFT], 1);
    __syncthreads();
    int c = cnt[t];
    lscan[t] = c;
    __syncthreads();
    for (int off = 1; off < MAXNB; off <<= 1) {
        int v = (t >= off) ? lscan[t - off] : 0;
        __syncthreads();
        lscan[t] += v;
        __syncthreads();
    }
    lstart[t] = lscan[t] - c;
    int gb = 0;
    if (t < NB && c) gb = atomicAdd(&cursors[t], c);
    delta[t] = gb - lstart[t];
    cnt[t] = 0;
    __syncthreads();
    for (int j = t; j < nHere; j += 512) {
        int dv = dst[start + j], sv = src[start + j];
        int b = dv >> BINSHIFT;
        int r = atomicAdd(&cnt[b], 1);
        stage[lstart[b] + r] = ((unsigned)(dv & (BINSZ - 1)) << 20) | (unsigned)sv;
    }
    __syncthreads();
    int wave = t >> 6, lane = t & 63;
    for (int b = wave; b < NB; b += 8) {
        int s0 = lstart[b], dlt = delta[b], s1 = s0 + cnt[b];
        for (int j = s0 + lane; j < s1; j += 64)
            binned[dlt + j] = stage[j];
    }
}

// B (R5): split reduce — nt binned loads (protect x in L2), 8-deep gather MLP.
__global__ __launch_bounds__(512, 8)
void reduce_split(const unsigned int* __restrict__ binned,
                  const int* __restrict__ offsets,
                  const float* __restrict__ xin,
                  float* __restrict__ partials, int PAD) {
    __shared__ float acc[BINSZ];
    int bin = blockIdx.x >> SPLITSH;
    int seg = blockIdx.x & (SPLIT - 1);
    int t = threadIdx.x;

    #pragma unroll
    for (int k = 0; k < BINSZ / 512; ++k) acc[t + k * 512] = 0.f;
    __syncthreads();

    int s = offsets[bin];
    int e = offsets[bin + 1];
    int c = e - s;
    int s_k = s + (int)(((long long)c * seg) >> SPLITSH);
    int e_k = s + (int)(((long long)c * (seg + 1)) >> SPLITSH);

    int a0 = (s_k + 3) & ~3;
    if (a0 > e_k) a0 = e_k;
    int a1 = e_k & ~3;
    if (a1 < a0) a1 = a0;

    for (int i = s_k + t; i < a0; i += 512) {
        unsigned p = binned[i];
        atomicAdd(&acc[p >> 20], xin[p & 0xFFFFFu]);
    }
    const u32x4* b4 = reinterpret_cast<const u32x4*>(binned);
    int q = (a0 >> 2) + t;
    int q1 = a1 >> 2;
    for (; q + 512 < q1; q += 1024) {
        u32x4 pA = __builtin_nontemporal_load(&b4[q]);
        u32x4 pB = __builtin_nontemporal_load(&b4[q + 512]);
        float v0 = xin[pA.x & 0xFFFFFu];
        float v1 = xin[pA.y & 0xFFFFFu];
        float v2 = xin[pA.z & 0xFFFFFu];
        float v3 = xin[pA.w & 0xFFFFFu];
        float v4 = xin[pB.x & 0xFFFFFu];
        float v5 = xin[pB.y & 0xFFFFFu];
        float v6 = xin[pB.z & 0xFFFFFu];
        float v7 = xin[pB.w & 0xFFFFFu];
        atomicAdd(&acc[pA.x >> 20], v0);
        atomicAdd(&acc[pA.y >> 20], v1);
        atomicAdd(&acc[pA.z >> 20], v2);
        atomicAdd(&acc[pA.w >> 20], v3);
        atomicAdd(&acc[pB.x >> 20], v4);
        atomicAdd(&acc[pB.y >> 20], v5);
        atomicAdd(&acc[pB.z >> 20], v6);
        atomicAdd(&acc[pB.w >> 20], v7);
    }
    for (; q < q1; q += 512) {
        u32x4 p = __builtin_nontemporal_load(&b4[q]);
        float v0 = xin[p.x & 0xFFFFFu];
        float v1 = xin[p.y & 0xFFFFFu];
        float v2 = xin[p.z & 0xFFFFFu];
        float v3 = xin[p.w & 0xFFFFFu];
        atomicAdd(&acc[p.x >> 20], v0);
        atomicAdd(&acc[p.y >> 20], v1);
        atomicAdd(&acc[p.z >> 20], v2);
        atomicAdd(&acc[p.w >> 20], v3);
    }
    for (int i = a1 + t; i < e_k; i += 512) {
        unsigned p = binned[i];
        atomicAdd(&acc[p >> 20], xin[p & 0xFFFFFu]);
    }
    __syncthreads();

    float* po = partials + (size_t)seg * PAD + (bin << BINSHIFT);
    const f32x4* accv = reinterpret_cast<const f32x4*>(acc);
    f32x4* pov = reinterpret_cast<f32x4*>(po);
    #pragma unroll
    for (int k = 0; k < BINSZ / 4 / 512; ++k)
        __builtin_nontemporal_store(accv[t + k * 512], &pov[t + k * 512]);
}

// C: combine partials + fused epilogue
template <int FINAL>
__global__ void combine4(const float* __restrict__ partials, int PAD,
                         const float* __restrict__ wp, const float* __restrict__ bp,
                         float* __restrict__ xout, int n) {
    float w = wp[0];
    float bias = FINAL ? bp[0] : 0.f;
    int n4 = n >> 2;
    int tid = blockIdx.x * blockDim.x + threadIdx.x;
    const f32x4* p0 = reinterpret_cast<const f32x4*>(partials);
    const f32x4* p1 = reinterpret_cast<const f32x4*>(partials + (size_t)PAD);
    const f32x4* p2 = reinterpret_cast<const f32x4*>(partials + (size_t)2 * PAD);
    const f32x4* p3 = reinterpret_cast<const f32x4*>(partials + (size_t)3 * PAD);
    if (tid < n4) {
        f32x4 a = __builtin_nontemporal_load(&p0[tid]);
        f32x4 b = __builtin_nontemporal_load(&p1[tid]);
        f32x4 cc = __builtin_nontemporal_load(&p2[tid]);
        f32x4 d = __builtin_nontemporal_load(&p3[tid]);
        f32x4 v;
        v.x = fmaxf((a.x + b.x + cc.x + d.x) * w, 0.f);
        v.y = fmaxf((a.y + b.y + cc.y + d.y) * w, 0.f);
        v.z = fmaxf((a.z + b.z + cc.z + d.z) * w, 0.f);
        v.w = fmaxf((a.w + b.w + cc.w + d.w) * w, 0.f);
        if (FINAL) {
            v.x = 1.f / (1.f + __expf(-(v.x + bias)));
            v.y = 1.f / (1.f + __expf(-(v.y + bias)));
            v.z = 1.f / (1.f + __expf(-(v.z + bias)));
            v.w = 1.f / (1.f + __expf(-(v.w + bias)));
        }
        reinterpret_cast<f32x4*>(xout)[tid] = v;
    }
    int base = n4 << 2;
    int r = base + tid;
    if (tid < n - base) {
        float sv = partials[r] + partials[(size_t)PAD + r] +
                   partials[(size_t)2 * PAD + r] + partials[(size_t)3 * PAD + r];
        float h = fmaxf(sv * w, 0.f);
        if (FINAL) h = 1.f / (1.f + __expf(-(h + bias)));
        xout[r] = h;
    }
}

// B fallback: one block per bin, fused epilogue (ws too small for partials)
template <int FINAL>
__global__ void reduce_bins(const unsigned int* __restrict__ binned,
                            const int* __restrict__ offsets,
                            const float* __restrict__ xin,
                            const float* __restrict__ wp,
                            const float* __restrict__ bp,
                            float* __restrict__ xout, int n) {
    __shared__ float acc[BINSZ];
    int b = blockIdx.x;
    for (int t = threadIdx.x; t < BINSZ; t += blockDim.x) acc[t] = 0.f;
    __syncthreads();
    int start = offsets[b];
    int end = offsets[b + 1];
    int nth = blockDim.x;
    int i = start + threadIdx.x;
    for (; i < end; i += nth) {
        unsigned p = binned[i];
        atomicAdd(&acc[p >> 20], xin[p & 0xFFFFFu]);
    }
    __syncthreads();
    float w = wp[0];
    float bias = FINAL ? bp[0] : 0.f;
    int nodeBase = b << BINSHIFT;
    for (int t = threadIdx.x; t < BINSZ; t += blockDim.x) {
        int node = nodeBase + t;
        if (node < n) {
            float h = fmaxf(acc[t] * w, 0.f);
            if (FINAL) h = 1.f / (1.f + __expf(-(h + bias)));
            xout[node] = h;
        }
    }
}

// ========================= fallback (round-1) path =========================

__global__ void scatter_add4(const float* __restrict__ x,
                             const int* __restrict__ src,
                             const int* __restrict__ dst,
                             float* __restrict__ agg,
                             int nE4, int nE) {
    int tid = blockIdx.x * blockDim.x + threadIdx.x;
    int stride = gridDim.x * blockDim.x;
    for (int i = tid; i < nE4; i += stride) {
        int4 s = reinterpret_cast<const int4*>(src)[i];
        int4 d = reinterpret_cast<const int4*>(dst)[i];
        atomicAdd(&agg[d.x], x[s.x]);
        atomicAdd(&agg[d.y], x[s.y]);
        atomicAdd(&agg[d.z], x[s.z]);
        atomicAdd(&agg[d.w], x[s.w]);
    }
    int e = nE4 * 4 + tid;
    if (e < nE) atomicAdd(&agg[dst[e]], x[src[e]]);
}

__global__ void relu_scale4(float* __restrict__ a, const float* __restrict__ w, int n4) {
    float wv = w[0];
    int tid = blockIdx.x * blockDim.x + threadIdx.x;
    int stride = gridDim.x * blockDim.x;
    for (int i = tid; i < n4; i += stride) {
        float4 v = reinterpret_cast<float4*>(a)[i];
        v.x = fmaxf(v.x * wv, 0.0f);
        v.y = fmaxf(v.y * wv, 0.0f);
        v.z = fmaxf(v.z * wv, 0.0f);
        v.w = fmaxf(v.w * wv, 0.0f);
        reinterpret_cast<float4*>(a)[i] = v;
    }
}

__global__ void finish4(float* __restrict__ o, const float* __restrict__ w,
                        const float* __restrict__ bias, int n4) {
    float wv = w[0];
    float b = bias[0];
    int tid = blockIdx.x * blockDim.x + threadIdx.x;
    int stride = gridDim.x * blockDim.x;
    for (int i = tid; i < n4; i += stride) {
        float4 v = reinterpret_cast<float4*>(o)[i];
        float sx = fmaxf(v.x * wv, 0.0f) + b;
        float sy = fmaxf(v.y * wv, 0.0f) + b;
        float sz = fmaxf(v.z * wv, 0.0f) + b;
        float sw = fmaxf(v.w * wv, 0.0f) + b;
        v.x = 1.0f / (1.0f + __expf(-sx));
        v.y = 1.0f / (1.0f + __expf(-sy));
        v.z = 1.0f / (1.0f + __expf(-sz));
        v.w = 1.0f / (1.0f + __expf(-sw));
        reinterpret_cast<float4*>(o)[i] = v;
    }
}

// ========================= launcher =========================

extern "C" void kernel_launch(void* const* d_in, const int* in_sizes, int n_in,
                              void* d_out, int out_size, void* d_ws, size_t ws_size,
                              hipStream_t stream) {
    const float* x    = (const float*)d_in[0];
    const int*   ei   = (const int*)d_in[1];
    const float* w    = (const float*)d_in[2];
    const float* bias = (const float*)d_in[3];

    int n  = in_sizes[0];
    int nE = in_sizes[1] / 2;
    const int* src = ei;
    const int* dst = ei + nE;
    float* out = (float*)d_out;

    int NB = (n + BINSZ - 1) >> BINSHIFT;
    int PAD = NB << BINSHIFT;

    size_t sz_binned = ((size_t)nE * 4 + 255) & ~(size_t)255;
    size_t sz_meta   = ((size_t)(MAXNB * 2 + MAXNB + 1) * 4 + 255) & ~(size_t)255;
    size_t sz_node   = ((size_t)PAD * 4 + 255) & ~(size_t)255;
    size_t need_bin   = sz_binned + sz_meta + sz_node;
    size_t need_split = sz_binned + sz_meta + sz_node * (1 + SPLIT);

    bool can_bin   = (n <= (1 << 20)) && (NB <= MAXNB) && (ws_size >= need_bin);
    bool can_split = can_bin && (ws_size >= need_split);

    if (can_bin) {
        unsigned int* binned = (unsigned int*)d_ws;
        int* counts  = (int*)((char*)d_ws + sz_binned);
        int* offsets = counts + MAXNB;
        int* cursors = offsets + MAXNB + 1;
        float* h1    = (float*)((char*)d_ws + sz_binned + sz_meta);
        float* parts = (float*)((char*)d_ws + sz_binned + sz_meta + sz_node);

        hipMemsetAsync(counts, 0, MAXNB * sizeof(int), stream);

        dim3 blk256(256), blk512(512), blk1024(STH2);
        count_bins<<<4096, blk256, 0, stream>>>(dst, nE, NB, counts);
        scan_bins<<<1, MAXNB, 0, stream>>>(counts, offsets, cursors, NB);

        int nFull = nE / SCHUNK;
        int tail0 = nFull * SCHUNK;
        if (nFull)
            scatter_staged2<<<nFull, blk1024, 0, stream>>>(src, dst, NB, cursors, binned);
        if (tail0 < nE)
            scatter_tail<<<1, blk512, 0, stream>>>(src, dst, tail0, nE, NB, cursors, binned);

        if (can_split) {
            int cblocks = (n / 4 + 255) / 256 + 1;
            reduce_split<<<NB * SPLIT, blk512, 0, stream>>>(binned, offsets, x, parts, PAD);
            combine4<0><<<cblocks, blk256, 0, stream>>>(parts, PAD, w + 0, bias, h1, n);
            reduce_split<<<NB * SPLIT, blk512, 0, stream>>>(binned, offsets, h1, parts, PAD);
            combine4<1><<<cblocks, blk256, 0, stream>>>(parts, PAD, w + 1, bias, out, n);
        } else {
            reduce_bins<0><<<NB, blk512, 0, stream>>>(binned, offsets, x, w + 0, bias, h1, n);
            reduce_bins<1><<<NB, blk512, 0, stream>>>(binned, offsets, h1, w + 1, bias, out, n);
        }
    } else {
        float* agg1 = (float*)d_ws;
        hipMemsetAsync(agg1, 0, (size_t)n * sizeof(float), stream);
        hipMemsetAsync(out,  0, (size_t)n * sizeof(float), stream);
        int nE4 = nE / 4;
        dim3 blk(256);
        int eblocks = (nE4 + 255) / 256; if (eblocks > 4096) eblocks = 4096;
        int n4 = n / 4;
        int nblocks = (n4 + 255) / 256; if (nblocks > 2048) nblocks = 2048;
        scatter_add4<<<eblocks, blk, 0, stream>>>(x, src, dst, agg1, nE4, nE);
        relu_scale4<<<nblocks, blk, 0, stream>>>(agg1, w + 0, n4);
        scatter_add4<<<eblocks, blk, 0, stream>>>(agg1, src, dst, out, nE4, nE);
        finish4<<<nblocks, blk, 0, stream>>>(out, w + 1, bias, n4);
    }
}

// Round 6
// 318.659 us; speedup vs baseline: 1.2837x; 1.2837x over previous
//
#include <hip/hip_runtime.h>
#include <math.h>

// ---------------------------------------------------------------------------
// 2-layer graph conv (1-wide features), atomic-free via dst-binned counting
// sort (once, reused by both layers) + per-bin LDS accumulation.
//   layer: agg[v] = sum_{(u->v)} x[u];  x = relu(agg * w[i])
//   out   = sigmoid(x + bias)
// Packing: N <= 2^20, BINSZ=2048 -> entry = (dst_low11 << 20) | src20
// R6: revert to R3/R4 best components (2-pass scatter_staged @512thr, fused
//     reduce_bins, no nt hints, no SPLIT). One change: reduce_bins at 1024
//     threads for 2x wave-level latency hiding + uint4 binned loads.
// ---------------------------------------------------------------------------

#define BINSHIFT 11
#define BINSZ    2048
#define MAXNB    512
#define SCHUNK   16384
#define STHREADS 512
#define RTH      1024

typedef unsigned u32x4 __attribute__((ext_vector_type(4)));

// A1: per-bin edge counts (LDS histogram, one global atomic per block per bin)
__global__ void count_bins(const int* __restrict__ dst, int nE, int NB,
                           int* __restrict__ counts) {
    __shared__ int h[MAXNB];
    for (int t = threadIdx.x; t < MAXNB; t += blockDim.x) h[t] = 0;
    __syncthreads();
    int tid = blockIdx.x * blockDim.x + threadIdx.x;
    int stride = gridDim.x * blockDim.x;
    int nE4 = nE >> 2;
    for (int i = tid; i < nE4; i += stride) {
        int4 d = reinterpret_cast<const int4*>(dst)[i];
        atomicAdd(&h[d.x >> BINSHIFT], 1);
        atomicAdd(&h[d.y >> BINSHIFT], 1);
        atomicAdd(&h[d.z >> BINSHIFT], 1);
        atomicAdd(&h[d.w >> BINSHIFT], 1);
    }
    for (int e = (nE4 << 2) + tid; e < nE; e += stride)
        atomicAdd(&h[dst[e] >> BINSHIFT], 1);
    __syncthreads();
    for (int t = threadIdx.x; t < NB; t += blockDim.x)
        if (h[t]) atomicAdd(&counts[t], h[t]);
}

// A2: exclusive scan of NB (<=512) counts -> offsets[NB+1], cursors
__global__ void scan_bins(const int* __restrict__ counts, int* __restrict__ offsets,
                          int* __restrict__ cursors, int NB) {
    __shared__ int s[MAXNB];
    int t = threadIdx.x;
    int c = (t < NB) ? counts[t] : 0;
    s[t] = c;
    __syncthreads();
    for (int off = 1; off < MAXNB; off <<= 1) {
        int v = (t >= off) ? s[t - off] : 0;
        __syncthreads();
        s[t] += v;
        __syncthreads();
    }
    if (t < NB) {
        int excl = s[t] - c;
        offsets[t] = excl;
        cursors[t] = excl;
        if (t == NB - 1) offsets[NB] = s[t];
    }
}

// A3: LDS-staged scatter (R4 version — best known: 97 us).
__global__ __launch_bounds__(STHREADS, 2)
void scatter_staged(const int* __restrict__ src, const int* __restrict__ dst,
                    int nE, int NB, int* __restrict__ cursors,
                    unsigned int* __restrict__ binned) {
    __shared__ unsigned int stage[SCHUNK];
    __shared__ int cnt[MAXNB];
    __shared__ int lstart[MAXNB];
    __shared__ int lscan[MAXNB];
    __shared__ int delta[MAXNB];

    int t = threadIdx.x;
    int cb = blockIdx.x * SCHUNK;
    int nHere = nE - cb;
    if (nHere > SCHUNK) nHere = SCHUNK;

    cnt[t] = 0;
    __syncthreads();

    if (nHere == SCHUNK) {
        const int4* d4 = reinterpret_cast<const int4*>(dst + cb);
        #pragma unroll
        for (int k = 0; k < SCHUNK / 4 / STHREADS; ++k) {
            int4 d = d4[k * STHREADS + t];
            atomicAdd(&cnt[d.x >> BINSHIFT], 1);
            atomicAdd(&cnt[d.y >> BINSHIFT], 1);
            atomicAdd(&cnt[d.z >> BINSHIFT], 1);
            atomicAdd(&cnt[d.w >> BINSHIFT], 1);
        }
    } else {
        for (int j = t; j < nHere; j += STHREADS)
            atomicAdd(&cnt[dst[cb + j] >> BINSHIFT], 1);
    }
    __syncthreads();

    int c = cnt[t];
    lscan[t] = c;
    __syncthreads();
    for (int off = 1; off < MAXNB; off <<= 1) {
        int v = (t >= off) ? lscan[t - off] : 0;
        __syncthreads();
        lscan[t] += v;
        __syncthreads();
    }
    lstart[t] = lscan[t] - c;

    int gb = 0;
    if (t < NB && c) gb = atomicAdd(&cursors[t], c);
    delta[t] = gb - lstart[t];
    cnt[t] = 0;
    __syncthreads();

    if (nHere == SCHUNK) {
        const int4* d4 = reinterpret_cast<const int4*>(dst + cb);
        const int4* s4 = reinterpret_cast<const int4*>(src + cb);
        #pragma unroll
        for (int k = 0; k < SCHUNK / 4 / STHREADS; ++k) {
            int4 d = d4[k * STHREADS + t];
            int4 s = s4[k * STHREADS + t];
            int b, r;
            b = d.x >> BINSHIFT; r = atomicAdd(&cnt[b], 1);
            stage[lstart[b] + r] = ((unsigned)(d.x & (BINSZ - 1)) << 20) | (unsigned)s.x;
            b = d.y >> BINSHIFT; r = atomicAdd(&cnt[b], 1);
            stage[lstart[b] + r] = ((unsigned)(d.y & (BINSZ - 1)) << 20) | (unsigned)s.y;
            b = d.z >> BINSHIFT; r = atomicAdd(&cnt[b], 1);
            stage[lstart[b] + r] = ((unsigned)(d.z & (BINSZ - 1)) << 20) | (unsigned)s.z;
            b = d.w >> BINSHIFT; r = atomicAdd(&cnt[b], 1);
            stage[lstart[b] + r] = ((unsigned)(d.w & (BINSZ - 1)) << 20) | (unsigned)s.w;
        }
    } else {
        for (int j = t; j < nHere; j += STHREADS) {
            int dv = dst[cb + j];
            int sv = src[cb + j];
            int b = dv >> BINSHIFT;
            int r = atomicAdd(&cnt[b], 1);
            stage[lstart[b] + r] = ((unsigned)(dv & (BINSZ - 1)) << 20) | (unsigned)sv;
        }
    }
    __syncthreads();

    int wave = t >> 6, lane = t & 63;
    for (int b = wave; b < NB; b += STHREADS / 64) {
        int s0 = lstart[b];
        int s1 = s0 + cnt[b];
        int dlt = delta[b];
        for (int j = s0 + lane; j < s1; j += 64)
            binned[dlt + j] = stage[j];
    }
}

// B (R6): one block per bin, 1024 threads, uint4 loads, fused epilogue.
template <int FINAL>
__global__ __launch_bounds__(RTH, 8)
void reduce_bins(const unsigned int* __restrict__ binned,
                 const int* __restrict__ offsets,
                 const float* __restrict__ xin,
                 const float* __restrict__ wp,
                 const float* __restrict__ bp,
                 float* __restrict__ xout, int n) {
    __shared__ float acc[BINSZ];
    int b = blockIdx.x;
    int t = threadIdx.x;
    acc[t] = 0.f;
    acc[t + RTH] = 0.f;
    __syncthreads();

    int s = offsets[b];
    int e = offsets[b + 1];
    int a0 = (s + 3) & ~3;
    if (a0 > e) a0 = e;
    int a1 = e & ~3;
    if (a1 < a0) a1 = a0;

    // scalar head (to 16B alignment)
    if (s + t < a0) {
        unsigned p = binned[s + t];
        atomicAdd(&acc[p >> 20], xin[p & 0xFFFFFu]);
    }
    // vector mid: 1 uint4 = 4 gathers in flight per instruction
    const u32x4* b4 = reinterpret_cast<const u32x4*>(binned);
    int q1 = a1 >> 2;
    for (int q = (a0 >> 2) + t; q < q1; q += RTH) {
        u32x4 p = b4[q];
        float v0 = xin[p.x & 0xFFFFFu];
        float v1 = xin[p.y & 0xFFFFFu];
        float v2 = xin[p.z & 0xFFFFFu];
        float v3 = xin[p.w & 0xFFFFFu];
        atomicAdd(&acc[p.x >> 20], v0);
        atomicAdd(&acc[p.y >> 20], v1);
        atomicAdd(&acc[p.z >> 20], v2);
        atomicAdd(&acc[p.w >> 20], v3);
    }
    // scalar tail
    if (a1 + t < e) {
        unsigned p = binned[a1 + t];
        atomicAdd(&acc[p >> 20], xin[p & 0xFFFFFu]);
    }
    __syncthreads();

    float w = wp[0];
    float bias = FINAL ? bp[0] : 0.f;
    int nodeBase = b << BINSHIFT;
    #pragma unroll
    for (int k = 0; k < BINSZ / RTH; ++k) {
        int node = nodeBase + t + k * RTH;
        if (node < n) {
            float h = fmaxf(acc[t + k * RTH] * w, 0.f);
            if (FINAL) h = 1.f / (1.f + __expf(-(h + bias)));
            xout[node] = h;
        }
    }
}

// ========================= fallback (round-1) path =========================

__global__ void scatter_add4(const float* __restrict__ x,
                             const int* __restrict__ src,
                             const int* __restrict__ dst,
                             float* __restrict__ agg,
                             int nE4, int nE) {
    int tid = blockIdx.x * blockDim.x + threadIdx.x;
    int stride = gridDim.x * blockDim.x;
    for (int i = tid; i < nE4; i += stride) {
        int4 s = reinterpret_cast<const int4*>(src)[i];
        int4 d = reinterpret_cast<const int4*>(dst)[i];
        atomicAdd(&agg[d.x], x[s.x]);
        atomicAdd(&agg[d.y], x[s.y]);
        atomicAdd(&agg[d.z], x[s.z]);
        atomicAdd(&agg[d.w], x[s.w]);
    }
    int e = nE4 * 4 + tid;
    if (e < nE) atomicAdd(&agg[dst[e]], x[src[e]]);
}

__global__ void relu_scale4(float* __restrict__ a, const float* __restrict__ w, int n4) {
    float wv = w[0];
    int tid = blockIdx.x * blockDim.x + threadIdx.x;
    int stride = gridDim.x * blockDim.x;
    for (int i = tid; i < n4; i += stride) {
        float4 v = reinterpret_cast<float4*>(a)[i];
        v.x = fmaxf(v.x * wv, 0.0f);
        v.y = fmaxf(v.y * wv, 0.0f);
        v.z = fmaxf(v.z * wv, 0.0f);
        v.w = fmaxf(v.w * wv, 0.0f);
        reinterpret_cast<float4*>(a)[i] = v;
    }
}

__global__ void finish4(float* __restrict__ o, const float* __restrict__ w,
                        const float* __restrict__ bias, int n4) {
    float wv = w[0];
    float b = bias[0];
    int tid = blockIdx.x * blockDim.x + threadIdx.x;
    int stride = gridDim.x * blockDim.x;
    for (int i = tid; i < n4; i += stride) {
        float4 v = reinterpret_cast<float4*>(o)[i];
        float sx = fmaxf(v.x * wv, 0.0f) + b;
        float sy = fmaxf(v.y * wv, 0.0f) + b;
        float sz = fmaxf(v.z * wv, 0.0f) + b;
        float sw = fmaxf(v.w * wv, 0.0f) + b;
        v.x = 1.0f / (1.0f + __expf(-sx));
        v.y = 1.0f / (1.0f + __expf(-sy));
        v.z = 1.0f / (1.0f + __expf(-sz));
        v.w = 1.0f / (1.0f + __expf(-sw));
        reinterpret_cast<float4*>(o)[i] = v;
    }
}

// ========================= launcher =========================

extern "C" void kernel_launch(void* const* d_in, const int* in_sizes, int n_in,
                              void* d_out, int out_size, void* d_ws, size_t ws_size,
                              hipStream_t stream) {
    const float* x    = (const float*)d_in[0];
    const int*   ei   = (const int*)d_in[1];
    const float* w    = (const float*)d_in[2];
    const float* bias = (const float*)d_in[3];

    int n  = in_sizes[0];
    int nE = in_sizes[1] / 2;
    const int* src = ei;
    const int* dst = ei + nE;
    float* out = (float*)d_out;

    int NB = (n + BINSZ - 1) >> BINSHIFT;

    // ws layout: binned[nE] | counts[512] | offsets[513] | cursors[512] | h1[n]
    size_t sz_binned = ((size_t)nE * 4 + 255) & ~(size_t)255;
    size_t sz_meta   = ((size_t)(MAXNB * 2 + MAXNB + 1) * 4 + 255) & ~(size_t)255;
    size_t sz_h1     = ((size_t)n * 4 + 255) & ~(size_t)255;
    size_t need      = sz_binned + sz_meta + sz_h1;

    bool can_bin = (n <= (1 << 20)) && (NB <= MAXNB) && (ws_size >= need);

    if (can_bin) {
        unsigned int* binned = (unsigned int*)d_ws;
        int* counts  = (int*)((char*)d_ws + sz_binned);
        int* offsets = counts + MAXNB;
        int* cursors = offsets + MAXNB + 1;
        float* h1    = (float*)((char*)d_ws + sz_binned + sz_meta);

        hipMemsetAsync(counts, 0, MAXNB * sizeof(int), stream);

        dim3 blk256(256), blk512(512), blk1024(RTH);
        count_bins<<<2048, blk256, 0, stream>>>(dst, nE, NB, counts);
        scan_bins<<<1, MAXNB, 0, stream>>>(counts, offsets, cursors, NB);
        int nChunks = (nE + SCHUNK - 1) / SCHUNK;
        scatter_staged<<<nChunks, blk512, 0, stream>>>(src, dst, nE, NB, cursors, binned);

        reduce_bins<0><<<NB, blk1024, 0, stream>>>(binned, offsets, x, w + 0, bias, h1, n);
        reduce_bins<1><<<NB, blk1024, 0, stream>>>(binned, offsets, h1, w + 1, bias, out, n);
    } else {
        float* agg1 = (float*)d_ws;
        hipMemsetAsync(agg1, 0, (size_t)n * sizeof(float), stream);
        hipMemsetAsync(out,  0, (size_t)n * sizeof(float), stream);
        int nE4 = nE / 4;
        dim3 blk(256);
        int eblocks = (nE4 + 255) / 256; if (eblocks > 4096) eblocks = 4096;
        int n4 = n / 4;
        int nblocks = (n4 + 255) / 256; if (nblocks > 2048) nblocks = 2048;
        scatter_add4<<<eblocks, blk, 0, stream>>>(x, src, dst, agg1, nE4, nE);
        relu_scale4<<<nblocks, blk, 0, stream>>>(agg1, w + 0, n4);
        scatter_add4<<<eblocks, blk, 0, stream>>>(agg1, src, dst, out, nE4, nE);
        finish4<<<nblocks, blk, 0, stream>>>(out, w + 1, bias, n4);
    }
}